// Round 14
// baseline (475.065 us; speedup 1.0000x reference)
//
#include <hip/hip_runtime.h>

#define N_OBJ 16384
#define N_REL 32768
#define HID 512
#define POOL 4096
#define NCLS 151
#define NRELCLS 51

#define AS1 __attribute__((address_space(1)))
#define AS3 __attribute__((address_space(3)))

// fused kernel LDS map (bytes), total 65536 (64KB -> 2 blocks/CU):
//   K-loop (BK=32): A slots 2x8KB @0,8192 ; B slots 2x16KB @16384,32768 (48KB)
//   epilogue (staging dead): Pb[128 rows][512B] = 64KB @0
#define LDSSZ 65536

typedef __attribute__((ext_vector_type(8))) short short8;
typedef __attribute__((ext_vector_type(4))) float f32x4;

__device__ __forceinline__ unsigned short f2bf(float x) {
    unsigned u = __float_as_uint(x);
    u += 0x7fff + ((u >> 16) & 1);   // round-to-nearest-even
    return (unsigned short)(u >> 16);
}

// ---------- generic f32 -> bf16 convert, 8 elems/thread ----------
__global__ void cvt_kernel(const float* __restrict__ in, unsigned short* __restrict__ out, long n8) {
    long i = (long)blockIdx.x * blockDim.x + threadIdx.x;
    if (i >= n8) return;
    const float4* p = (const float4*)in;
    float4 a = p[2 * i], b = p[2 * i + 1];
    short8 o;
    o[0] = f2bf(a.x); o[1] = f2bf(a.y); o[2] = f2bf(a.z); o[3] = f2bf(a.w);
    o[4] = f2bf(b.x); o[5] = f2bf(b.y); o[6] = f2bf(b.z); o[7] = f2bf(b.w);
    ((short8*)out)[i] = o;
}

// ---------- W_rel (51x4096) -> padded bf16 (64x4096), rows >=51 zero ----------
__global__ void cvt_wrel_kernel(const float* __restrict__ W, unsigned short* __restrict__ out) {
    int gid = blockIdx.x * 256 + threadIdx.x;
    int row = gid >> 9;
    int c8 = (gid & 511) << 3;
    short8 o = {};
    if (row < NRELCLS) {
        const float* src = W + (long)row * POOL + c8;
        float4 a = *(const float4*)src, b = *(const float4*)(src + 4);
        o[0] = f2bf(a.x); o[1] = f2bf(a.y); o[2] = f2bf(a.z); o[3] = f2bf(a.w);
        o[4] = f2bf(b.x); o[5] = f2bf(b.y); o[6] = f2bf(b.z); o[7] = f2bf(b.w);
    }
    *(short8*)(out + (long)row * POOL + c8) = o;
}

// ---------- stage a [128 rows][64 cols] bf16 tile into LDS (GEMM1 helper) ----------
__device__ __forceinline__ void stage_tile128x64(const unsigned short* __restrict__ src,
                                                 unsigned short* lds,
                                                 int row0, int rowStrideElems, int col0,
                                                 int wave, int lane) {
    const char* s = (const char*)(src + (long)row0 * rowStrideElems + col0);
    long strideB = (long)rowStrideElems * 2;
#pragma unroll
    for (int is = 0; is < 4; ++is) {
        int issue = wave * 4 + is;
        const char* g = s + (long)(issue * 8 + (lane >> 3)) * strideB + (lane & 7) * 16;
        __builtin_amdgcn_global_load_lds((const AS1 void*)g,
                                         (AS3 void*)((char*)lds + issue * 1024),
                                         16, 0, 0);
    }
}

// ---------- GEMM1: edge_rep = edge_ctx(16384x512) @ W_emb(1024x512)^T + b, bf16 out ----------
__global__ __launch_bounds__(256) void gemm1_kernel(const unsigned short* __restrict__ A,
                                                    const unsigned short* __restrict__ B,
                                                    const float* __restrict__ bias,
                                                    unsigned short* __restrict__ C) {
    __shared__ __align__(16) unsigned short At[128 * 64];
    __shared__ __align__(16) unsigned short Bt[128 * 64];
    int row0 = blockIdx.x * 128, col0 = blockIdx.y * 128;
    int tid = threadIdx.x, wave = tid >> 6, lane = tid & 63;
    int wr = (wave >> 1) * 64, wc = (wave & 1) * 64;
    int lrow = lane & 15, lko = (lane >> 4) * 8;
    f32x4 acc[4][4] = {};
    for (int kt = 0; kt < HID / 64; ++kt) {
        stage_tile128x64(A, At, row0, HID, kt * 64, wave, lane);
        stage_tile128x64(B, Bt, col0, HID, kt * 64, wave, lane);
        __syncthreads();
#pragma unroll
        for (int ks = 0; ks < 2; ++ks) {
            short8 af[4], bf[4];
#pragma unroll
            for (int mi = 0; mi < 4; ++mi) af[mi] = *(const short8*)(At + (wr + 16 * mi + lrow) * 64 + ks * 32 + lko);
#pragma unroll
            for (int ni = 0; ni < 4; ++ni) bf[ni] = *(const short8*)(Bt + (wc + 16 * ni + lrow) * 64 + ks * 32 + lko);
#pragma unroll
            for (int mi = 0; mi < 4; ++mi)
#pragma unroll
                for (int ni = 0; ni < 4; ++ni)
                    acc[mi][ni] = __builtin_amdgcn_mfma_f32_16x16x32_bf16(af[mi], bf[ni], acc[mi][ni], 0, 0, 0);
        }
        __syncthreads();
    }
#pragma unroll
    for (int mi = 0; mi < 4; ++mi)
#pragma unroll
        for (int ni = 0; ni < 4; ++ni)
#pragma unroll
            for (int i = 0; i < 4; ++i) {
                int r = row0 + wr + 16 * mi + 4 * (lane >> 4) + i;
                int c = col0 + wc + 16 * ni + lrow;
                C[(long)r * 1024 + c] = f2bf(acc[mi][ni][i] + bias[c]);
            }
}

// ---------- reduce: out[r][c] = b_rel[c] + freq_bias[oh,ot,c] + sum_p part[p][r][c] ----------
__global__ __launch_bounds__(512) void reduce_kernel(const float* __restrict__ part,
                                                     const int* __restrict__ pair_idx,
                                                     const int* __restrict__ obj_preds,
                                                     const float* __restrict__ b_rel,
                                                     const float* __restrict__ freq_bias,
                                                     float* __restrict__ out) {
    int r = blockIdx.x * 8 + (threadIdx.x >> 6);
    int lane = threadIdx.x & 63;
    if (lane < NRELCLS) {
        int h = pair_idx[2 * r], t = pair_idx[2 * r + 1];
        long fidx = ((long)obj_preds[h] * NCLS + obj_preds[t]) * NRELCLS + lane;
        float s = b_rel[lane] + freq_bias[fidx];
#pragma unroll
        for (int p = 0; p < 16; ++p)
            s += part[((long)p * N_REL + r) * NRELCLS + lane];
        out[(long)r * NRELCLS + lane] = s;
    }
}

// ======================================================================
// fused: P = (concat(head[h],tail[t]) @ Wcat^T + bcat) * union ;
//        part[panel] = P_bf16 @ Wrel^T   (plain stores, r13-proven)
// NEW r14: BM=128, BN=256, 4 waves (wave tile 64x128), BK=32, LDS 64KB
// -> TWO independent blocks/CU: one block's K-loop MFMAs overlap the
// other's union-fill & vmcnt stalls (m114 mechanism; the r13-diagnosed
// exposed epilogue).  Schedule = r11-proven pattern: 2 phases/K-tile
// (16 MFMA each, ni-split), stage B(4)@P0 + A(2)@P1, counted vmcnt.
// FIFO ledger @P0(t): outstanding = tile_t(6) + t+1's B(4 just issued)
// = 10 -> vmcnt(4) retires exactly tile t's 6.  Slot sn=(t+1)&1 write
// safety: sn last read at tile t-1, each wave's reads consumed via its
// lgkmcnt(0)+MFMA before t-1's final barrier.
// Gather fused into A-staging (r10), XCD panel swizzle, Wrel-from-global.
// ======================================================================
__device__ __forceinline__ void stage_B(const char* __restrict__ Wcb, char* lds, int s, int t,
                                        int col0, int w, int lane) {
    int kb = t * 64;
#pragma unroll
    for (int i = 0; i < 4; ++i) {
        int obase = i * 4096 + w * 1024;     // wave-uniform LDS dest
        int o = obase + lane * 16;
        int row = o >> 6, cin = o & 63;
        int c = cin ^ ((row & 3) << 4);      // pre-swizzled source column
        __builtin_amdgcn_global_load_lds((const AS1 void*)(Wcb + (long)(col0 + row) * 2048 + kb + c),
                                         (AS3 void*)(lds + 16384 + s * 16384 + obase), 16, 0, 0);
    }
}

__device__ __forceinline__ void stage_A(const char* __restrict__ erepb, char* lds, int s, int t,
                                        const int* hA, const int* tA, const int* colbA, int w) {
    int kb = t * 64;
    int head = (kb < 1024);                  // head/tail half of concat (uniform per K-tile)
#pragma unroll
    for (int i = 0; i < 2; ++i) {
        int obase = i * 4096 + w * 1024;     // wave-uniform LDS dest
        int idx = head ? hA[i] : tA[i];
        __builtin_amdgcn_global_load_lds((const AS1 void*)(erepb + (long)idx * 2048 + kb + colbA[i]),
                                         (AS3 void*)(lds + s * 8192 + obase), 16, 0, 0);
    }
}

__global__ __launch_bounds__(256, 2) void fused_kernel(
    const unsigned short* __restrict__ erep,   // 16384x1024 bf16
    const unsigned short* __restrict__ Wcat,   // 4096x1024 bf16
    const unsigned short* __restrict__ Wrelp,  // 64x4096 bf16 (padded)
    const float* __restrict__ unionf,          // 32768x4096 f32
    const float* __restrict__ bcat,            // 4096
    const int* __restrict__ pair_idx,          // 32768x2 int32
    float* __restrict__ part) {                // 16x32768x51 f32 partials
    __shared__ __align__(16) char lds[LDSSZ];
    // bijective XCD-panel swizzle: 4096 blocks; xcd = bid&7 owns panels {2x,2x+1}
    int bid = blockIdx.x;
    int xcd = bid & 7, j = bid >> 3;            // j in [0,512)
    int panel = (xcd << 1) | (j >> 8);          // [0,16)
    int row0 = (j & 255) * 128, col0 = panel * 256;
    int tid = threadIdx.x, w = tid >> 6, lane = tid & 63;
    int wr = (w >> 1) * 64, wc = (w & 1) * 128; // wave tile 64 rows x 128 cols
    int lrow = lane & 15, lcb = (lane >> 4) * 16;
    const char* erepb = (const char*)erep;
    const char* Wcb = (const char*)Wcat;
    f32x4 acc2[4][8] = {};

    // ---- per-thread A-staging constants: 2 fixed rows, h/t, swizzled col ----
    int hA[2], tA[2], colbA[2];
#pragma unroll
    for (int i = 0; i < 2; ++i) {
        int o = i * 4096 + w * 1024 + lane * 16;
        int ar = o >> 6, cin = o & 63;
        colbA[i] = cin ^ ((ar & 3) << 4);       // pre-swizzled source column
        hA[i] = pair_idx[2 * (row0 + ar)];
        tA[i] = pair_idx[2 * (row0 + ar) + 1];
    }

    // ---- prologue: K-tile 0 -> slot 0 (B 4 + A 2 = 6 in flight) ----
    stage_B(Wcb, lds, 0, 0, col0, w, lane);
    stage_A(erepb, lds, 0, 0, hA, tA, colbA, w);

    // ---- K-loop: 32 K-tiles x 2 phases (16 MFMA each, ni-split) ----
    for (int t = 0; t < 32; ++t) {
        const char* A = lds + (t & 1) * 8192;
        const char* B = lds + 16384 + (t & 1) * 16384;
        int sn = (t + 1) & 1;
        short8 aF[4], bF[4];
        // ---- P0: stage B(t+1), counted wait, publish, MFMA ni 0-3 ----
        if (t < 31) {
            stage_B(Wcb, lds, sn, t + 1, col0, w, lane);
            asm volatile("s_waitcnt vmcnt(4)" ::: "memory");   // retire tile t's 6
        } else {
            asm volatile("s_waitcnt vmcnt(0)" ::: "memory");   // last tile
        }
        __builtin_amdgcn_s_barrier();           // publish slot t&1
        __builtin_amdgcn_sched_barrier(0);
#pragma unroll
        for (int m = 0; m < 4; ++m) {
            int r = wr + 16 * m + lrow;
            aF[m] = *(const short8*)(A + r * 64 + (lcb ^ ((r & 3) << 4)));
        }
#pragma unroll
        for (int ni = 0; ni < 4; ++ni) {
            int r = wc + 16 * ni + lrow;
            bF[ni] = *(const short8*)(B + r * 64 + (lcb ^ ((r & 3) << 4)));
        }
        asm volatile("s_waitcnt lgkmcnt(0)" ::: "memory");
        __builtin_amdgcn_sched_barrier(0);
        __builtin_amdgcn_s_setprio(1);
#pragma unroll
        for (int m = 0; m < 4; ++m)
#pragma unroll
            for (int ni = 0; ni < 4; ++ni)
                acc2[m][ni] = __builtin_amdgcn_mfma_f32_16x16x32_bf16(aF[m], bF[ni], acc2[m][ni], 0, 0, 0);
        __builtin_amdgcn_s_setprio(0);
        __builtin_amdgcn_s_barrier();
        // ---- P1: read bF ni 4-7, stage A(t+1), MFMA ni 4-7 ----
#pragma unroll
        for (int ni = 0; ni < 4; ++ni) {
            int r = wc + 16 * (ni + 4) + lrow;
            bF[ni] = *(const short8*)(B + r * 64 + (lcb ^ ((r & 3) << 4)));
        }
        if (t < 31) stage_A(erepb, lds, sn, t + 1, hA, tA, colbA, w);
        __builtin_amdgcn_s_barrier();
        __builtin_amdgcn_sched_barrier(0);
        asm volatile("s_waitcnt lgkmcnt(0)" ::: "memory");
        __builtin_amdgcn_sched_barrier(0);
        __builtin_amdgcn_s_setprio(1);
#pragma unroll
        for (int m = 0; m < 4; ++m)
#pragma unroll
            for (int ni = 0; ni < 4; ++ni)
                acc2[m][ni + 4] = __builtin_amdgcn_mfma_f32_16x16x32_bf16(aF[m], bF[ni], acc2[m][ni + 4], 0, 0, 0);
        __builtin_amdgcn_s_setprio(0);
        __builtin_amdgcn_s_barrier();
    }

    // ---- all staging reads consumed -> region reusable as Pb ----
    asm volatile("s_waitcnt lgkmcnt(0)" ::: "memory");
    __builtin_amdgcn_sched_barrier(0);
    __builtin_amdgcn_s_barrier();
    __builtin_amdgcn_sched_barrier(0);

    // ---- Pb fill: all 4 waves, each its own 64x128 quadrant of Pb[128][256] ----
    {
        float bcv[8];
#pragma unroll
        for (int ni = 0; ni < 8; ++ni) bcv[ni] = bcat[col0 + wc + 16 * ni + lrow];
#pragma unroll
        for (int mi = 0; mi < 4; ++mi)
#pragma unroll
            for (int ni = 0; ni < 8; ++ni) {
                int pcol = wc + 16 * ni + lrow;          // [0,256) within panel
#pragma unroll
                for (int i = 0; i < 4; ++i) {
                    int prow = wr + 16 * mi + 4 * (lane >> 4) + i;
                    float u = __builtin_nontemporal_load(
                        &unionf[(long)(row0 + prow) * 4096 + col0 + pcol]);
                    *(unsigned short*)(lds + prow * 512 + ((pcol * 2) ^ ((prow & 7) << 4)))
                        = f2bf((acc2[mi][ni][i] + bcv[ni]) * u);
                }
            }
    }
    asm volatile("s_waitcnt lgkmcnt(0)" ::: "memory");
    __builtin_amdgcn_sched_barrier(0);
    __builtin_amdgcn_s_barrier();
    __builtin_amdgcn_sched_barrier(0);

    // ---- GEMM3: acc3 += Pb(128x256) @ Wrel_panel(64x256)^T ; wave owns rows w*32..+31
    //      Wrel B-frags straight from global (tiny, L2-hot). K = 256 -> 8 ks-steps.
    f32x4 acc3[2][4] = {};
    const char* Wrb = (const char*)Wrelp;
#pragma unroll
    for (int ks = 0; ks < 8; ++ks) {
        int cb2 = ks * 64 + lcb;                 // byte offset in 512B row
        short8 wb[4], pa[2];
#pragma unroll
        for (int ni = 0; ni < 4; ++ni) {
            int r2 = 16 * ni + lrow;
            wb[ni] = *(const short8*)(Wrb + (long)r2 * 8192 + col0 * 2 + cb2);
        }
#pragma unroll
        for (int mi = 0; mi < 2; ++mi) {
            int r2 = w * 32 + 16 * mi + lrow;
            pa[mi] = *(const short8*)(lds + r2 * 512 + (cb2 ^ ((r2 & 7) << 4)));
        }
#pragma unroll
        for (int mi = 0; mi < 2; ++mi)
#pragma unroll
            for (int ni = 0; ni < 4; ++ni)
                acc3[mi][ni] = __builtin_amdgcn_mfma_f32_16x16x32_bf16(pa[mi], wb[ni], acc3[mi][ni], 0, 0, 0);
    }
    // ---- store partial (contention-free; reduce_kernel sums the 16 planes) ----
#pragma unroll
    for (int mi = 0; mi < 2; ++mi)
#pragma unroll
        for (int ni = 0; ni < 4; ++ni)
#pragma unroll
            for (int i = 0; i < 4; ++i) {
                int r = row0 + w * 32 + 16 * mi + 4 * (lane >> 4) + i;
                int cc = 16 * ni + lrow;
                if (cc < NRELCLS)
                    part[((long)panel * N_REL + r) * NRELCLS + cc] = acc3[mi][ni][i];
            }
}

extern "C" void kernel_launch(void* const* d_in, const int* in_sizes, int n_in,
                              void* d_out, int out_size, void* d_ws, size_t ws_size,
                              hipStream_t stream) {
    const float* edge_ctx  = (const float*)d_in[0];
    const float* unionf    = (const float*)d_in[1];
    const int*   pair_idx  = (const int*)d_in[2];
    const int*   obj_preds = (const int*)d_in[3];
    const float* W_emb     = (const float*)d_in[4];
    const float* b_emb     = (const float*)d_in[5];
    const float* W_cat     = (const float*)d_in[6];
    const float* b_cat     = (const float*)d_in[7];
    const float* W_rel     = (const float*)d_in[8];
    const float* b_rel     = (const float*)d_in[9];
    const float* freq_bias = (const float*)d_in[10];
    float* out = (float*)d_out;

    char* ws = (char*)d_ws;
    unsigned short* ecb   = (unsigned short*)ws; ws += (size_t)N_OBJ * HID * 2;   // 16MB
    unsigned short* Wembb = (unsigned short*)ws; ws += (size_t)1024 * HID * 2;    // 1MB
    unsigned short* Wcatb = (unsigned short*)ws; ws += (size_t)POOL * 1024 * 2;   // 8MB
    unsigned short* Wrelb = (unsigned short*)ws; ws += (size_t)64 * POOL * 2;     // 0.5MB
    unsigned short* erep  = (unsigned short*)ws; ws += (size_t)N_OBJ * 1024 * 2;  // 32MB
    float*          part  = (float*)ws;          ws += (size_t)16 * N_REL * NRELCLS * 4; // 107MB

    cvt_kernel<<<4096, 256, 0, stream>>>(edge_ctx, ecb, (long)N_OBJ * HID / 8);
    cvt_kernel<<<256, 256, 0, stream>>>(W_emb, Wembb, (long)1024 * HID / 8);
    cvt_kernel<<<2048, 256, 0, stream>>>(W_cat, Wcatb, (long)POOL * 1024 / 8);
    cvt_wrel_kernel<<<128, 256, 0, stream>>>(W_rel, Wrelb);
    gemm1_kernel<<<dim3(128, 8), 256, 0, stream>>>(ecb, Wembb, b_emb, erep);
    fused_kernel<<<4096, 256, 0, stream>>>(erep, Wcatb, Wrelb, unionf, b_cat, pair_idx, part);
    reduce_kernel<<<4096, 512, 0, stream>>>(part, pair_idx, obj_preds, b_rel, freq_bias, out);
}

// Round 15
// 471.109 us; speedup vs baseline: 1.0084x; 1.0084x over previous
//
#include <hip/hip_runtime.h>

#define N_OBJ 16384
#define N_REL 32768
#define HID 512
#define POOL 4096
#define NCLS 151
#define NRELCLS 51

#define AS1 __attribute__((address_space(1)))
#define AS3 __attribute__((address_space(3)))

// fused kernel LDS map (bytes), total 131072 (128KB):
//   K-loop (BK=64): A slots 2x32KB @0,32768 ; B slots 2x32KB @65536,98304
//   epilogue (staging dead): Pb[256 rows][512B] 128KB @0  (Wrel read from global)
#define LDSSZ 131072

typedef __attribute__((ext_vector_type(8))) short short8;
typedef __attribute__((ext_vector_type(4))) float f32x4;

__device__ __forceinline__ unsigned short f2bf(float x) {
    unsigned u = __float_as_uint(x);
    u += 0x7fff + ((u >> 16) & 1);   // round-to-nearest-even
    return (unsigned short)(u >> 16);
}

// ---------- generic f32 -> bf16 convert, 8 elems/thread ----------
__global__ void cvt_kernel(const float* __restrict__ in, unsigned short* __restrict__ out, long n8) {
    long i = (long)blockIdx.x * blockDim.x + threadIdx.x;
    if (i >= n8) return;
    const float4* p = (const float4*)in;
    float4 a = p[2 * i], b = p[2 * i + 1];
    short8 o;
    o[0] = f2bf(a.x); o[1] = f2bf(a.y); o[2] = f2bf(a.z); o[3] = f2bf(a.w);
    o[4] = f2bf(b.x); o[5] = f2bf(b.y); o[6] = f2bf(b.z); o[7] = f2bf(b.w);
    ((short8*)out)[i] = o;
}

// ---------- W_rel (51x4096) -> padded bf16 (64x4096), rows >=51 zero ----------
__global__ void cvt_wrel_kernel(const float* __restrict__ W, unsigned short* __restrict__ out) {
    int gid = blockIdx.x * 256 + threadIdx.x;
    int row = gid >> 9;
    int c8 = (gid & 511) << 3;
    short8 o = {};
    if (row < NRELCLS) {
        const float* src = W + (long)row * POOL + c8;
        float4 a = *(const float4*)src, b = *(const float4*)(src + 4);
        o[0] = f2bf(a.x); o[1] = f2bf(a.y); o[2] = f2bf(a.z); o[3] = f2bf(a.w);
        o[4] = f2bf(b.x); o[5] = f2bf(b.y); o[6] = f2bf(b.z); o[7] = f2bf(b.w);
    }
    *(short8*)(out + (long)row * POOL + c8) = o;
}

// ---------- stage a [128 rows][64 cols] bf16 tile into LDS (GEMM1 helper) ----------
__device__ __forceinline__ void stage_tile128x64(const unsigned short* __restrict__ src,
                                                 unsigned short* lds,
                                                 int row0, int rowStrideElems, int col0,
                                                 int wave, int lane) {
    const char* s = (const char*)(src + (long)row0 * rowStrideElems + col0);
    long strideB = (long)rowStrideElems * 2;
#pragma unroll
    for (int is = 0; is < 4; ++is) {
        int issue = wave * 4 + is;
        const char* g = s + (long)(issue * 8 + (lane >> 3)) * strideB + (lane & 7) * 16;
        __builtin_amdgcn_global_load_lds((const AS1 void*)g,
                                         (AS3 void*)((char*)lds + issue * 1024),
                                         16, 0, 0);
    }
}

// ---------- GEMM1: edge_rep = edge_ctx(16384x512) @ W_emb(1024x512)^T + b, bf16 out ----------
__global__ __launch_bounds__(256) void gemm1_kernel(const unsigned short* __restrict__ A,
                                                    const unsigned short* __restrict__ B,
                                                    const float* __restrict__ bias,
                                                    unsigned short* __restrict__ C) {
    __shared__ __align__(16) unsigned short At[128 * 64];
    __shared__ __align__(16) unsigned short Bt[128 * 64];
    int row0 = blockIdx.x * 128, col0 = blockIdx.y * 128;
    int tid = threadIdx.x, wave = tid >> 6, lane = tid & 63;
    int wr = (wave >> 1) * 64, wc = (wave & 1) * 64;
    int lrow = lane & 15, lko = (lane >> 4) * 8;
    f32x4 acc[4][4] = {};
    for (int kt = 0; kt < HID / 64; ++kt) {
        stage_tile128x64(A, At, row0, HID, kt * 64, wave, lane);
        stage_tile128x64(B, Bt, col0, HID, kt * 64, wave, lane);
        __syncthreads();
#pragma unroll
        for (int ks = 0; ks < 2; ++ks) {
            short8 af[4], bf[4];
#pragma unroll
            for (int mi = 0; mi < 4; ++mi) af[mi] = *(const short8*)(At + (wr + 16 * mi + lrow) * 64 + ks * 32 + lko);
#pragma unroll
            for (int ni = 0; ni < 4; ++ni) bf[ni] = *(const short8*)(Bt + (wc + 16 * ni + lrow) * 64 + ks * 32 + lko);
#pragma unroll
            for (int mi = 0; mi < 4; ++mi)
#pragma unroll
                for (int ni = 0; ni < 4; ++ni)
                    acc[mi][ni] = __builtin_amdgcn_mfma_f32_16x16x32_bf16(af[mi], bf[ni], acc[mi][ni], 0, 0, 0);
        }
        __syncthreads();
    }
#pragma unroll
    for (int mi = 0; mi < 4; ++mi)
#pragma unroll
        for (int ni = 0; ni < 4; ++ni)
#pragma unroll
            for (int i = 0; i < 4; ++i) {
                int r = row0 + wr + 16 * mi + 4 * (lane >> 4) + i;
                int c = col0 + wc + 16 * ni + lrow;
                C[(long)r * 1024 + c] = f2bf(acc[mi][ni][i] + bias[c]);
            }
}

// ---------- reduce: out[r][c] = b_rel[c] + freq_bias[oh,ot,c] + sum_p part[r][p][c] ----------
// part layout [row][panel][51]: the 16 partials of a row are a contiguous
// 3264B block -> pure streaming read (r13's [panel][row][51] scattered the
// 16 reads across 6.7MB-strided planes).
__global__ __launch_bounds__(512) void reduce_kernel(const float* __restrict__ part,
                                                     const int* __restrict__ pair_idx,
                                                     const int* __restrict__ obj_preds,
                                                     const float* __restrict__ b_rel,
                                                     const float* __restrict__ freq_bias,
                                                     float* __restrict__ out) {
    int r = blockIdx.x * 8 + (threadIdx.x >> 6);
    int lane = threadIdx.x & 63;
    if (lane < NRELCLS) {
        int h = pair_idx[2 * r], t = pair_idx[2 * r + 1];
        long fidx = ((long)obj_preds[h] * NCLS + obj_preds[t]) * NRELCLS + lane;
        float s = b_rel[lane] + freq_bias[fidx];
        const float* pr = part + (long)r * 16 * NRELCLS;
#pragma unroll
        for (int p = 0; p < 16; ++p)
            s += pr[p * NRELCLS + lane];
        out[(long)r * NRELCLS + lane] = s;
    }
}

// ======================================================================
// fused: P = (concat(head[h],tail[t]) @ Wcat^T + bcat) * union ;
//        part[row][panel] = P_bf16 @ Wrel^T   (plain stores, r13-proven)
// EXACT r13 structure (best total: 467us): BM=256, BN=256, 8 waves,
// BK=64, 2 LDS slots, m201-style 4-phase K-tile schedule, stage halves
// at P0 and P2, vmcnt(4) counted wait, gather fused into A-staging,
// XCD-panel swizzle, single-pass epilogue, Wrel-from-global,
// contention-free partial stores.  ONLY change vs r13: partial layout
// [row][panel][51] for reduce-side streaming locality.
// ======================================================================
__device__ __forceinline__ void stage_half(const char* __restrict__ erepb, const char* __restrict__ Wcb,
                                           char* lds, int slot, int t, int i0, int col0,
                                           const int* hA, const int* tA,
                                           const int* arowA, const int* colbA, int w) {
    int kb = t * 128;                    // byte offset of K-tile in 2048B row
    int head = (kb < 1024);              // head/tail half of concat (uniform per K-tile)
#pragma unroll
    for (int i = i0; i < i0 + 2; ++i) {
        int obase = i * 8192 + w * 1024; // wave-uniform LDS dest
        int idx = head ? hA[i] : tA[i];
        __builtin_amdgcn_global_load_lds((const AS1 void*)(erepb + (long)idx * 2048 + kb + colbA[i]),
                                         (AS3 void*)(lds + slot * 32768 + obase), 16, 0, 0);
        __builtin_amdgcn_global_load_lds((const AS1 void*)(Wcb + (long)(col0 + arowA[i]) * 2048 + kb + colbA[i]),
                                         (AS3 void*)(lds + 65536 + slot * 32768 + obase), 16, 0, 0);
    }
}

__device__ __forceinline__ void read_bfrags(const char* B, int wc, int lrow, int lcb, short8 bF[4][2]) {
#pragma unroll
    for (int ni = 0; ni < 4; ++ni)
#pragma unroll
        for (int ks = 0; ks < 2; ++ks) {
            int r = wc + 16 * ni + lrow;
            bF[ni][ks] = *(const short8*)(B + r * 128 + ((ks * 64 + lcb) ^ ((r & 7) << 4)));
        }
}

__device__ __forceinline__ void read_afrags(const char* A, int p, int wr, int lrow, int lcb, short8 aF[2][2]) {
#pragma unroll
    for (int m = 0; m < 2; ++m)
#pragma unroll
        for (int ks = 0; ks < 2; ++ks) {
            int r = wr + 16 * (2 * p + m) + lrow;
            aF[m][ks] = *(const short8*)(A + r * 128 + ((ks * 64 + lcb) ^ ((r & 7) << 4)));
        }
}

__device__ __forceinline__ void mfma16(int p, short8 aF[2][2], short8 bF[4][2], f32x4 acc[8][4]) {
    __builtin_amdgcn_s_setprio(1);
#pragma unroll
    for (int m = 0; m < 2; ++m)
#pragma unroll
        for (int ni = 0; ni < 4; ++ni)
#pragma unroll
            for (int ks = 0; ks < 2; ++ks)
                acc[2 * p + m][ni] = __builtin_amdgcn_mfma_f32_16x16x32_bf16(aF[m][ks], bF[ni][ks], acc[2 * p + m][ni], 0, 0, 0);
    __builtin_amdgcn_s_setprio(0);
}

__global__ __launch_bounds__(512, 1) void fused_kernel(
    const unsigned short* __restrict__ erep,   // 16384x1024 bf16
    const unsigned short* __restrict__ Wcat,   // 4096x1024 bf16
    const unsigned short* __restrict__ Wrelp,  // 64x4096 bf16 (padded)
    const float* __restrict__ unionf,          // 32768x4096 f32
    const float* __restrict__ bcat,            // 4096
    const int* __restrict__ pair_idx,          // 32768x2 int32
    float* __restrict__ part) {                // 32768x16x51 f32 partials
    __shared__ __align__(16) char lds[LDSSZ];
    // bijective XCD-panel swizzle: 2048 blocks; xcd = bid&7 owns panels {2x,2x+1}
    int bid = blockIdx.x;
    int xcd = bid & 7, j = bid >> 3;            // j in [0,256)
    int panel = (xcd << 1) | (j >> 7);          // [0,16)
    int row0 = (j & 127) * 256, col0 = panel * 256;
    int tid = threadIdx.x, w = tid >> 6, lane = tid & 63;
    int wr = (w >> 2) * 128, wc = (w & 3) * 64;
    int lrow = lane & 15, lcb = (lane >> 4) * 16;
    const char* erepb = (const char*)erep;
    const char* Wcb = (const char*)Wcat;
    f32x4 acc2[8][4] = {};

    // ---- per-thread A/B-staging constants: 4 fixed rows, h/t, swizzled col ----
    int hA[4], tA[4], arowA[4], colbA[4];
#pragma unroll
    for (int i = 0; i < 4; ++i) {
        int o = i * 8192 + w * 1024 + lane * 16;
        int ar = o >> 7, cin = o & 127;
        arowA[i] = ar;
        colbA[i] = cin ^ ((ar & 7) << 4);       // pre-swizzled source column
        hA[i] = pair_idx[2 * (row0 + ar)];
        tA[i] = pair_idx[2 * (row0 + ar) + 1];
    }

    // ---- prologue: K-tile 0 (both halves) -> slot 0; in-flight = 8 ----
    stage_half(erepb, Wcb, lds, 0, 0, 0, col0, hA, tA, arowA, colbA, w);
    stage_half(erepb, Wcb, lds, 0, 0, 2, col0, hA, tA, arowA, colbA, w);

    // ---- K-loop: 16 K-tiles x 4 phases ----
    for (int t = 0; t < 16; ++t) {
        const char* A = lds + (t & 1) * 32768;
        const char* B = lds + 65536 + (t & 1) * 32768;
        int sn = (t + 1) & 1;                   // staging slot for K-tile t+1 (dead)
        short8 bF[4][2];
#pragma unroll
        for (int p = 0; p < 4; ++p) {
            short8 aF[2][2];
            if (p == 0) {
                if (t < 15) {
                    stage_half(erepb, Wcb, lds, sn, t + 1, 0, col0, hA, tA, arowA, colbA, w);
                    asm volatile("s_waitcnt vmcnt(4)" ::: "memory");   // retire K-tile t's 8
                } else {
                    asm volatile("s_waitcnt vmcnt(0)" ::: "memory");   // last tile
                }
                __builtin_amdgcn_s_barrier();   // publish slot t&1
                __builtin_amdgcn_sched_barrier(0);
                read_bfrags(B, wc, lrow, lcb, bF);
                read_afrags(A, 0, wr, lrow, lcb, aF);
            } else {
                read_afrags(A, p, wr, lrow, lcb, aF);   // slot already published
                if (p == 2 && t < 15)
                    stage_half(erepb, Wcb, lds, sn, t + 1, 2, col0, hA, tA, arowA, colbA, w);
                __builtin_amdgcn_s_barrier();
                __builtin_amdgcn_sched_barrier(0);
            }
            asm volatile("s_waitcnt lgkmcnt(0)" ::: "memory");
            __builtin_amdgcn_sched_barrier(0);
            mfma16(p, aF, bF, acc2);
            __builtin_amdgcn_s_barrier();
        }
    }

    // ---- all staging reads consumed -> region reusable as Pb ----
    asm volatile("s_waitcnt lgkmcnt(0)" ::: "memory");
    __builtin_amdgcn_sched_barrier(0);
    __builtin_amdgcn_s_barrier();
    __builtin_amdgcn_sched_barrier(0);

    // ---- Pb fill: ALL 8 waves, each its own 128x64 quadrant of Pb[256][256] ----
    {
        float bcv[4];
#pragma unroll
        for (int ni = 0; ni < 4; ++ni) bcv[ni] = bcat[col0 + wc + 16 * ni + lrow];
#pragma unroll
        for (int mi = 0; mi < 8; ++mi)
#pragma unroll
            for (int ni = 0; ni < 4; ++ni) {
                int pcol = wc + 16 * ni + lrow;          // [0,256) within panel
#pragma unroll
                for (int i = 0; i < 4; ++i) {
                    int prow = wr + 16 * mi + 4 * (lane >> 4) + i;
                    float u = __builtin_nontemporal_load(
                        &unionf[(long)(row0 + prow) * 4096 + col0 + pcol]);
                    *(unsigned short*)(lds + prow * 512 + ((pcol * 2) ^ ((prow & 7) << 4)))
                        = f2bf((acc2[mi][ni][i] + bcv[ni]) * u);
                }
            }
    }
    asm volatile("s_waitcnt lgkmcnt(0)" ::: "memory");
    __builtin_amdgcn_sched_barrier(0);
    __builtin_amdgcn_s_barrier();
    __builtin_amdgcn_sched_barrier(0);

    // ---- GEMM3: acc3 += Pb(256x256) @ Wrel_panel(64x256)^T ; wave owns rows w*32..+31
    //      Wrel B-frags straight from global (tiny, L2-hot). K = 256 -> 8 ks-steps.
    f32x4 acc3[2][4] = {};
    const char* Wrb = (const char*)Wrelp;
#pragma unroll
    for (int ks = 0; ks < 8; ++ks) {
        int cb2 = ks * 64 + lcb;                 // byte offset in 512B row
        short8 wb[4], pa[2];
#pragma unroll
        for (int ni = 0; ni < 4; ++ni) {
            int r2 = 16 * ni + lrow;
            wb[ni] = *(const short8*)(Wrb + (long)r2 * 8192 + col0 * 2 + cb2);
        }
#pragma unroll
        for (int mi = 0; mi < 2; ++mi) {
            int r2 = w * 32 + 16 * mi + lrow;
            pa[mi] = *(const short8*)(lds + r2 * 512 + (cb2 ^ ((r2 & 7) << 4)));
        }
#pragma unroll
        for (int mi = 0; mi < 2; ++mi)
#pragma unroll
            for (int ni = 0; ni < 4; ++ni)
                acc3[mi][ni] = __builtin_amdgcn_mfma_f32_16x16x32_bf16(pa[mi], wb[ni], acc3[mi][ni], 0, 0, 0);
    }
    // ---- store partial (contention-free; [row][panel][51] for reduce locality) ----
#pragma unroll
    for (int mi = 0; mi < 2; ++mi)
#pragma unroll
        for (int ni = 0; ni < 4; ++ni)
#pragma unroll
            for (int i = 0; i < 4; ++i) {
                int r = row0 + w * 32 + 16 * mi + 4 * (lane >> 4) + i;
                int cc = 16 * ni + lrow;
                if (cc < NRELCLS)
                    part[((long)r * 16 + panel) * NRELCLS + cc] = acc3[mi][ni][i];
            }
}

extern "C" void kernel_launch(void* const* d_in, const int* in_sizes, int n_in,
                              void* d_out, int out_size, void* d_ws, size_t ws_size,
                              hipStream_t stream) {
    const float* edge_ctx  = (const float*)d_in[0];
    const float* unionf    = (const float*)d_in[1];
    const int*   pair_idx  = (const int*)d_in[2];
    const int*   obj_preds = (const int*)d_in[3];
    const float* W_emb     = (const float*)d_in[4];
    const float* b_emb     = (const float*)d_in[5];
    const float* W_cat     = (const float*)d_in[6];
    const float* b_cat     = (const float*)d_in[7];
    const float* W_rel     = (const float*)d_in[8];
    const float* b_rel     = (const float*)d_in[9];
    const float* freq_bias = (const float*)d_in[10];
    float* out = (float*)d_out;

    char* ws = (char*)d_ws;
    unsigned short* ecb   = (unsigned short*)ws; ws += (size_t)N_OBJ * HID * 2;   // 16MB
    unsigned short* Wembb = (unsigned short*)ws; ws += (size_t)1024 * HID * 2;    // 1MB
    unsigned short* Wcatb = (unsigned short*)ws; ws += (size_t)POOL * 1024 * 2;   // 8MB
    unsigned short* Wrelb = (unsigned short*)ws; ws += (size_t)64 * POOL * 2;     // 0.5MB
    unsigned short* erep  = (unsigned short*)ws; ws += (size_t)N_OBJ * 1024 * 2;  // 32MB
    float*          part  = (float*)ws;          ws += (size_t)N_REL * 16 * NRELCLS * 4; // 107MB

    cvt_kernel<<<4096, 256, 0, stream>>>(edge_ctx, ecb, (long)N_OBJ * HID / 8);
    cvt_kernel<<<256, 256, 0, stream>>>(W_emb, Wembb, (long)1024 * HID / 8);
    cvt_kernel<<<2048, 256, 0, stream>>>(W_cat, Wcatb, (long)POOL * 1024 / 8);
    cvt_wrel_kernel<<<128, 256, 0, stream>>>(W_rel, Wrelb);
    gemm1_kernel<<<dim3(128, 8), 256, 0, stream>>>(ecb, Wembb, b_emb, erep);
    fused_kernel<<<2048, 512, 0, stream>>>(erep, Wcatb, Wrelb, unionf, b_cat, pair_idx, part);
    reduce_kernel<<<4096, 512, 0, stream>>>(part, pair_idx, obj_preds, b_rel, freq_bias, out);
}

// Round 16
// 466.148 us; speedup vs baseline: 1.0191x; 1.0106x over previous
//
#include <hip/hip_runtime.h>

#define N_OBJ 16384
#define N_REL 32768
#define HID 512
#define POOL 4096
#define NCLS 151
#define NRELCLS 51

#define AS1 __attribute__((address_space(1)))
#define AS3 __attribute__((address_space(3)))

// fused kernel LDS map (bytes), total 131072 (128KB):
//   K-loop (BK=64): A slots 2x32KB @0,32768 ; B slots 2x32KB @65536,98304
//   epilogue (staging dead): Pb[256 rows][512B] 128KB @0  (Wrel read from global)
#define LDSSZ 131072

typedef __attribute__((ext_vector_type(8))) short short8;
typedef __attribute__((ext_vector_type(4))) float f32x4;

__device__ __forceinline__ unsigned short f2bf(float x) {
    unsigned u = __float_as_uint(x);
    u += 0x7fff + ((u >> 16) & 1);   // round-to-nearest-even
    return (unsigned short)(u >> 16);
}

// ---------- generic f32 -> bf16 convert, 8 elems/thread ----------
__global__ void cvt_kernel(const float* __restrict__ in, unsigned short* __restrict__ out, long n8) {
    long i = (long)blockIdx.x * blockDim.x + threadIdx.x;
    if (i >= n8) return;
    const float4* p = (const float4*)in;
    float4 a = p[2 * i], b = p[2 * i + 1];
    short8 o;
    o[0] = f2bf(a.x); o[1] = f2bf(a.y); o[2] = f2bf(a.z); o[3] = f2bf(a.w);
    o[4] = f2bf(b.x); o[5] = f2bf(b.y); o[6] = f2bf(b.z); o[7] = f2bf(b.w);
    ((short8*)out)[i] = o;
}

// ---------- W_rel (51x4096) -> padded bf16 (64x4096), rows >=51 zero ----------
__global__ void cvt_wrel_kernel(const float* __restrict__ W, unsigned short* __restrict__ out) {
    int gid = blockIdx.x * 256 + threadIdx.x;
    int row = gid >> 9;
    int c8 = (gid & 511) << 3;
    short8 o = {};
    if (row < NRELCLS) {
        const float* src = W + (long)row * POOL + c8;
        float4 a = *(const float4*)src, b = *(const float4*)(src + 4);
        o[0] = f2bf(a.x); o[1] = f2bf(a.y); o[2] = f2bf(a.z); o[3] = f2bf(a.w);
        o[4] = f2bf(b.x); o[5] = f2bf(b.y); o[6] = f2bf(b.z); o[7] = f2bf(b.w);
    }
    *(short8*)(out + (long)row * POOL + c8) = o;
}

// ---------- stage a [128 rows][64 cols] bf16 tile into LDS (GEMM1 helper) ----------
__device__ __forceinline__ void stage_tile128x64(const unsigned short* __restrict__ src,
                                                 unsigned short* lds,
                                                 int row0, int rowStrideElems, int col0,
                                                 int wave, int lane) {
    const char* s = (const char*)(src + (long)row0 * rowStrideElems + col0);
    long strideB = (long)rowStrideElems * 2;
#pragma unroll
    for (int is = 0; is < 4; ++is) {
        int issue = wave * 4 + is;
        const char* g = s + (long)(issue * 8 + (lane >> 3)) * strideB + (lane & 7) * 16;
        __builtin_amdgcn_global_load_lds((const AS1 void*)g,
                                         (AS3 void*)((char*)lds + issue * 1024),
                                         16, 0, 0);
    }
}

// ---------- GEMM1: edge_rep = edge_ctx(16384x512) @ W_emb(1024x512)^T + b, bf16 out ----------
__global__ __launch_bounds__(256) void gemm1_kernel(const unsigned short* __restrict__ A,
                                                    const unsigned short* __restrict__ B,
                                                    const float* __restrict__ bias,
                                                    unsigned short* __restrict__ C) {
    __shared__ __align__(16) unsigned short At[128 * 64];
    __shared__ __align__(16) unsigned short Bt[128 * 64];
    int row0 = blockIdx.x * 128, col0 = blockIdx.y * 128;
    int tid = threadIdx.x, wave = tid >> 6, lane = tid & 63;
    int wr = (wave >> 1) * 64, wc = (wave & 1) * 64;
    int lrow = lane & 15, lko = (lane >> 4) * 8;
    f32x4 acc[4][4] = {};
    for (int kt = 0; kt < HID / 64; ++kt) {
        stage_tile128x64(A, At, row0, HID, kt * 64, wave, lane);
        stage_tile128x64(B, Bt, col0, HID, kt * 64, wave, lane);
        __syncthreads();
#pragma unroll
        for (int ks = 0; ks < 2; ++ks) {
            short8 af[4], bf[4];
#pragma unroll
            for (int mi = 0; mi < 4; ++mi) af[mi] = *(const short8*)(At + (wr + 16 * mi + lrow) * 64 + ks * 32 + lko);
#pragma unroll
            for (int ni = 0; ni < 4; ++ni) bf[ni] = *(const short8*)(Bt + (wc + 16 * ni + lrow) * 64 + ks * 32 + lko);
#pragma unroll
            for (int mi = 0; mi < 4; ++mi)
#pragma unroll
                for (int ni = 0; ni < 4; ++ni)
                    acc[mi][ni] = __builtin_amdgcn_mfma_f32_16x16x32_bf16(af[mi], bf[ni], acc[mi][ni], 0, 0, 0);
        }
        __syncthreads();
    }
#pragma unroll
    for (int mi = 0; mi < 4; ++mi)
#pragma unroll
        for (int ni = 0; ni < 4; ++ni)
#pragma unroll
            for (int i = 0; i < 4; ++i) {
                int r = row0 + wr + 16 * mi + 4 * (lane >> 4) + i;
                int c = col0 + wc + 16 * ni + lrow;
                C[(long)r * 1024 + c] = f2bf(acc[mi][ni][i] + bias[c]);
            }
}

// ---------- reduce: out[r][c] = b_rel[c] + freq_bias[oh,ot,c] + sum_p part[p][r][c] ----------
__global__ __launch_bounds__(512) void reduce_kernel(const float* __restrict__ part,
                                                     const int* __restrict__ pair_idx,
                                                     const int* __restrict__ obj_preds,
                                                     const float* __restrict__ b_rel,
                                                     const float* __restrict__ freq_bias,
                                                     float* __restrict__ out) {
    int r = blockIdx.x * 8 + (threadIdx.x >> 6);
    int lane = threadIdx.x & 63;
    if (lane < NRELCLS) {
        int h = pair_idx[2 * r], t = pair_idx[2 * r + 1];
        long fidx = ((long)obj_preds[h] * NCLS + obj_preds[t]) * NRELCLS + lane;
        float s = b_rel[lane] + freq_bias[fidx];
#pragma unroll
        for (int p = 0; p < 16; ++p)
            s += part[((long)p * N_REL + r) * NRELCLS + lane];
        out[(long)r * NRELCLS + lane] = s;
    }
}

// ======================================================================
// fused: P = (concat(head[h],tail[t]) @ Wcat^T + bcat) * union ;
//        part[panel] = P_bf16 @ Wrel^T   (plain stores -- NO atomics)
// EXACT r13 configuration (best measured: 466.6us total, fused 423us).
// BM=256, BN=256, 8 waves, BK=64, 2 LDS slots, m201-style 4-phase
// K-tile schedule, stage halves at P0 and P2, vmcnt(4) counted wait,
// gather fused into A-staging, XCD-panel swizzle, single-pass epilogue,
// Wrel-from-global, contention-free [panel][row][51] partial stores.
// Declared structural floor: r12 (fewer bytes), r14 (2 blocks/CU), r15
// (transposed partials) all neutral-or-worse; no counter at roofline --
// residual is the 2-wave/SIMD phase-latency cost of this decomposition.
// ======================================================================
__device__ __forceinline__ void stage_half(const char* __restrict__ erepb, const char* __restrict__ Wcb,
                                           char* lds, int slot, int t, int i0, int col0,
                                           const int* hA, const int* tA,
                                           const int* arowA, const int* colbA, int w) {
    int kb = t * 128;                    // byte offset of K-tile in 2048B row
    int head = (kb < 1024);              // head/tail half of concat (uniform per K-tile)
#pragma unroll
    for (int i = i0; i < i0 + 2; ++i) {
        int obase = i * 8192 + w * 1024; // wave-uniform LDS dest
        int idx = head ? hA[i] : tA[i];
        __builtin_amdgcn_global_load_lds((const AS1 void*)(erepb + (long)idx * 2048 + kb + colbA[i]),
                                         (AS3 void*)(lds + slot * 32768 + obase), 16, 0, 0);
        __builtin_amdgcn_global_load_lds((const AS1 void*)(Wcb + (long)(col0 + arowA[i]) * 2048 + kb + colbA[i]),
                                         (AS3 void*)(lds + 65536 + slot * 32768 + obase), 16, 0, 0);
    }
}

__device__ __forceinline__ void read_bfrags(const char* B, int wc, int lrow, int lcb, short8 bF[4][2]) {
#pragma unroll
    for (int ni = 0; ni < 4; ++ni)
#pragma unroll
        for (int ks = 0; ks < 2; ++ks) {
            int r = wc + 16 * ni + lrow;
            bF[ni][ks] = *(const short8*)(B + r * 128 + ((ks * 64 + lcb) ^ ((r & 7) << 4)));
        }
}

__device__ __forceinline__ void read_afrags(const char* A, int p, int wr, int lrow, int lcb, short8 aF[2][2]) {
#pragma unroll
    for (int m = 0; m < 2; ++m)
#pragma unroll
        for (int ks = 0; ks < 2; ++ks) {
            int r = wr + 16 * (2 * p + m) + lrow;
            aF[m][ks] = *(const short8*)(A + r * 128 + ((ks * 64 + lcb) ^ ((r & 7) << 4)));
        }
}

__device__ __forceinline__ void mfma16(int p, short8 aF[2][2], short8 bF[4][2], f32x4 acc[8][4]) {
    __builtin_amdgcn_s_setprio(1);
#pragma unroll
    for (int m = 0; m < 2; ++m)
#pragma unroll
        for (int ni = 0; ni < 4; ++ni)
#pragma unroll
            for (int ks = 0; ks < 2; ++ks)
                acc[2 * p + m][ni] = __builtin_amdgcn_mfma_f32_16x16x32_bf16(aF[m][ks], bF[ni][ks], acc[2 * p + m][ni], 0, 0, 0);
    __builtin_amdgcn_s_setprio(0);
}

__global__ __launch_bounds__(512, 1) void fused_kernel(
    const unsigned short* __restrict__ erep,   // 16384x1024 bf16
    const unsigned short* __restrict__ Wcat,   // 4096x1024 bf16
    const unsigned short* __restrict__ Wrelp,  // 64x4096 bf16 (padded)
    const float* __restrict__ unionf,          // 32768x4096 f32
    const float* __restrict__ bcat,            // 4096
    const int* __restrict__ pair_idx,          // 32768x2 int32
    float* __restrict__ part) {                // 16x32768x51 f32 partials
    __shared__ __align__(16) char lds[LDSSZ];
    // bijective XCD-panel swizzle: 2048 blocks; xcd = bid&7 owns panels {2x,2x+1}
    int bid = blockIdx.x;
    int xcd = bid & 7, j = bid >> 3;            // j in [0,256)
    int panel = (xcd << 1) | (j >> 7);          // [0,16)
    int row0 = (j & 127) * 256, col0 = panel * 256;
    int tid = threadIdx.x, w = tid >> 6, lane = tid & 63;
    int wr = (w >> 2) * 128, wc = (w & 3) * 64;
    int lrow = lane & 15, lcb = (lane >> 4) * 16;
    const char* erepb = (const char*)erep;
    const char* Wcb = (const char*)Wcat;
    f32x4 acc2[8][4] = {};

    // ---- per-thread A/B-staging constants: 4 fixed rows, h/t, swizzled col ----
    int hA[4], tA[4], arowA[4], colbA[4];
#pragma unroll
    for (int i = 0; i < 4; ++i) {
        int o = i * 8192 + w * 1024 + lane * 16;
        int ar = o >> 7, cin = o & 127;
        arowA[i] = ar;
        colbA[i] = cin ^ ((ar & 7) << 4);       // pre-swizzled source column
        hA[i] = pair_idx[2 * (row0 + ar)];
        tA[i] = pair_idx[2 * (row0 + ar) + 1];
    }

    // ---- prologue: K-tile 0 (both halves) -> slot 0; in-flight = 8 ----
    stage_half(erepb, Wcb, lds, 0, 0, 0, col0, hA, tA, arowA, colbA, w);
    stage_half(erepb, Wcb, lds, 0, 0, 2, col0, hA, tA, arowA, colbA, w);

    // ---- K-loop: 16 K-tiles x 4 phases ----
    for (int t = 0; t < 16; ++t) {
        const char* A = lds + (t & 1) * 32768;
        const char* B = lds + 65536 + (t & 1) * 32768;
        int sn = (t + 1) & 1;                   // staging slot for K-tile t+1 (dead)
        short8 bF[4][2];
#pragma unroll
        for (int p = 0; p < 4; ++p) {
            short8 aF[2][2];
            if (p == 0) {
                if (t < 15) {
                    stage_half(erepb, Wcb, lds, sn, t + 1, 0, col0, hA, tA, arowA, colbA, w);
                    asm volatile("s_waitcnt vmcnt(4)" ::: "memory");   // retire K-tile t's 8
                } else {
                    asm volatile("s_waitcnt vmcnt(0)" ::: "memory");   // last tile
                }
                __builtin_amdgcn_s_barrier();   // publish slot t&1
                __builtin_amdgcn_sched_barrier(0);
                read_bfrags(B, wc, lrow, lcb, bF);
                read_afrags(A, 0, wr, lrow, lcb, aF);
            } else {
                read_afrags(A, p, wr, lrow, lcb, aF);   // slot already published
                if (p == 2 && t < 15)
                    stage_half(erepb, Wcb, lds, sn, t + 1, 2, col0, hA, tA, arowA, colbA, w);
                __builtin_amdgcn_s_barrier();
                __builtin_amdgcn_sched_barrier(0);
            }
            asm volatile("s_waitcnt lgkmcnt(0)" ::: "memory");
            __builtin_amdgcn_sched_barrier(0);
            mfma16(p, aF, bF, acc2);
            __builtin_amdgcn_s_barrier();
        }
    }

    // ---- all staging reads consumed -> region reusable as Pb ----
    asm volatile("s_waitcnt lgkmcnt(0)" ::: "memory");
    __builtin_amdgcn_sched_barrier(0);
    __builtin_amdgcn_s_barrier();
    __builtin_amdgcn_sched_barrier(0);

    // ---- Pb fill: ALL 8 waves, each its own 128x64 quadrant of Pb[256][256] ----
    {
        float bcv[4];
#pragma unroll
        for (int ni = 0; ni < 4; ++ni) bcv[ni] = bcat[col0 + wc + 16 * ni + lrow];
#pragma unroll
        for (int mi = 0; mi < 8; ++mi)
#pragma unroll
            for (int ni = 0; ni < 4; ++ni) {
                int pcol = wc + 16 * ni + lrow;          // [0,256) within panel
#pragma unroll
                for (int i = 0; i < 4; ++i) {
                    int prow = wr + 16 * mi + 4 * (lane >> 4) + i;
                    float u = __builtin_nontemporal_load(
                        &unionf[(long)(row0 + prow) * 4096 + col0 + pcol]);
                    *(unsigned short*)(lds + prow * 512 + ((pcol * 2) ^ ((prow & 7) << 4)))
                        = f2bf((acc2[mi][ni][i] + bcv[ni]) * u);
                }
            }
    }
    asm volatile("s_waitcnt lgkmcnt(0)" ::: "memory");
    __builtin_amdgcn_sched_barrier(0);
    __builtin_amdgcn_s_barrier();
    __builtin_amdgcn_sched_barrier(0);

    // ---- GEMM3: acc3 += Pb(256x256) @ Wrel_panel(64x256)^T ; wave owns rows w*32..+31
    //      Wrel B-frags straight from global (tiny, L2-hot). K = 256 -> 8 ks-steps.
    f32x4 acc3[2][4] = {};
    const char* Wrb = (const char*)Wrelp;
#pragma unroll
    for (int ks = 0; ks < 8; ++ks) {
        int cb2 = ks * 64 + lcb;                 // byte offset in 512B row
        short8 wb[4], pa[2];
#pragma unroll
        for (int ni = 0; ni < 4; ++ni) {
            int r2 = 16 * ni + lrow;
            wb[ni] = *(const short8*)(Wrb + (long)r2 * 8192 + col0 * 2 + cb2);
        }
#pragma unroll
        for (int mi = 0; mi < 2; ++mi) {
            int r2 = w * 32 + 16 * mi + lrow;
            pa[mi] = *(const short8*)(lds + r2 * 512 + (cb2 ^ ((r2 & 7) << 4)));
        }
#pragma unroll
        for (int mi = 0; mi < 2; ++mi)
#pragma unroll
            for (int ni = 0; ni < 4; ++ni)
                acc3[mi][ni] = __builtin_amdgcn_mfma_f32_16x16x32_bf16(pa[mi], wb[ni], acc3[mi][ni], 0, 0, 0);
    }
    // ---- store partial (contention-free; reduce_kernel sums the 16 planes) ----
#pragma unroll
    for (int mi = 0; mi < 2; ++mi)
#pragma unroll
        for (int ni = 0; ni < 4; ++ni)
#pragma unroll
            for (int i = 0; i < 4; ++i) {
                int r = row0 + w * 32 + 16 * mi + 4 * (lane >> 4) + i;
                int cc = 16 * ni + lrow;
                if (cc < NRELCLS)
                    part[((long)panel * N_REL + r) * NRELCLS + cc] = acc3[mi][ni][i];
            }
}

extern "C" void kernel_launch(void* const* d_in, const int* in_sizes, int n_in,
                              void* d_out, int out_size, void* d_ws, size_t ws_size,
                              hipStream_t stream) {
    const float* edge_ctx  = (const float*)d_in[0];
    const float* unionf    = (const float*)d_in[1];
    const int*   pair_idx  = (const int*)d_in[2];
    const int*   obj_preds = (const int*)d_in[3];
    const float* W_emb     = (const float*)d_in[4];
    const float* b_emb     = (const float*)d_in[5];
    const float* W_cat     = (const float*)d_in[6];
    const float* b_cat     = (const float*)d_in[7];
    const float* W_rel     = (const float*)d_in[8];
    const float* b_rel     = (const float*)d_in[9];
    const float* freq_bias = (const float*)d_in[10];
    float* out = (float*)d_out;

    char* ws = (char*)d_ws;
    unsigned short* ecb   = (unsigned short*)ws; ws += (size_t)N_OBJ * HID * 2;   // 16MB
    unsigned short* Wembb = (unsigned short*)ws; ws += (size_t)1024 * HID * 2;    // 1MB
    unsigned short* Wcatb = (unsigned short*)ws; ws += (size_t)POOL * 1024 * 2;   // 8MB
    unsigned short* Wrelb = (unsigned short*)ws; ws += (size_t)64 * POOL * 2;     // 0.5MB
    unsigned short* erep  = (unsigned short*)ws; ws += (size_t)N_OBJ * 1024 * 2;  // 32MB
    float*          part  = (float*)ws;          ws += (size_t)16 * N_REL * NRELCLS * 4; // 107MB

    cvt_kernel<<<4096, 256, 0, stream>>>(edge_ctx, ecb, (long)N_OBJ * HID / 8);
    cvt_kernel<<<256, 256, 0, stream>>>(W_emb, Wembb, (long)1024 * HID / 8);
    cvt_kernel<<<2048, 256, 0, stream>>>(W_cat, Wcatb, (long)POOL * 1024 / 8);
    cvt_wrel_kernel<<<128, 256, 0, stream>>>(W_rel, Wrelb);
    gemm1_kernel<<<dim3(128, 8), 256, 0, stream>>>(ecb, Wembb, b_emb, erep);
    fused_kernel<<<2048, 512, 0, stream>>>(erep, Wcatb, Wrelb, unionf, b_cat, pair_idx, part);
    reduce_kernel<<<4096, 512, 0, stream>>>(part, pair_idx, obj_preds, b_rel, freq_bias, out);
}